// Round 1
// baseline (278.581 us; speedup 1.0000x reference)
//
#include <hip/hip_runtime.h>

#define N_PTS 100000
#define KSZ 9
#define C_IN 24
#define C_HID 144
#define C_OUT 24
#define G4_HID 36   // C_HID/4
#define G4_OUT 6    // C_OUT/4
#define EPSV 1e-5f

// workspace layout (in floats)
#define X1N_OFF   0
#define X1N_SIZE  ((N_PTS + 1) * C_HID)            // 14,400,144 (sentinel row at N)
#define X2_OFF    (X1N_OFF + X1N_SIZE)
#define X2_SIZE   (N_PTS * C_HID)                  // 14,400,000
#define ST_OFF    (X2_OFF + X2_SIZE)
// stats sub-offsets relative to ws base (all multiples of 32 -> 16B aligned)
#define MU1_O     (ST_OFF + 0)      // 24  (raw sums)
#define M1_O      (ST_OFF + 32)     // 576 (raw FtF sums)
#define SC1_O     (ST_OFF + 640)    // 144
#define SH1_O     (ST_OFF + 800)    // 144
#define SUM2_O    (ST_OFF + 960)    // 144
#define SQ2_O     (ST_OFF + 1120)   // 144
#define SC2_O     (ST_OFF + 1280)   // 144
#define SH2_O     (ST_OFF + 1440)   // 144
#define SUM3_O    (ST_OFF + 1600)   // 24
#define SQ3_O     (ST_OFF + 1632)   // 24
#define SC3_O     (ST_OFF + 1664)   // 24
#define SH3_O     (ST_OFF + 1696)   // 24
#define ST_SIZE   1728
#define Y3_OFF    0                 // y3 (N*24) aliases x1n (dead by then)

__device__ inline float4 f4z() { return make_float4(0.f, 0.f, 0.f, 0.f); }
__device__ inline float4 f4_add(float4 a, float4 b) {
    return make_float4(a.x + b.x, a.y + b.y, a.z + b.z, a.w + b.w);
}
__device__ inline float4 f4_fma4(float4 a, float4 b, float4 c) {
    return make_float4(fmaf(a.x, b.x, c.x), fmaf(a.y, b.y, c.y),
                       fmaf(a.z, b.z, c.z), fmaf(a.w, b.w, c.w));
}
__device__ inline float4 f4_fma_s(float s, float4 b, float4 c) {
    return make_float4(fmaf(s, b.x, c.x), fmaf(s, b.y, c.y),
                       fmaf(s, b.z, c.z), fmaf(s, b.w, c.w));
}
__device__ inline float4 f4_clamp6(float4 a) {
    return make_float4(fminf(fmaxf(a.x, 0.f), 6.f), fminf(fmaxf(a.y, 0.f), 6.f),
                       fminf(fmaxf(a.z, 0.f), 6.f), fminf(fmaxf(a.w, 0.f), 6.f));
}
__device__ inline float f4_get(const float4& v, int e) {
    return e == 0 ? v.x : (e == 1 ? v.y : (e == 2 ? v.z : v.w));
}

// ---- K0: zero stats + sentinel row (ws is re-poisoned to 0xAA before every call)
__global__ void k_init(float* ws) {
    int t = threadIdx.x;
    for (int i = t; i < ST_SIZE; i += 256) ws[ST_OFF + i] = 0.f;
    if (t < C_HID) ws[X1N_OFF + (size_t)N_PTS * C_HID + t] = 0.f;
}

// ---- K1: feats moments: mu1[24] = sum(F), M1[24x24] = F^T F (raw sums)
#define MROWS 128
__device__ inline float task_acc(const float* tile, int cnt, int task) {
    if (task < 576) {
        int i = task / 24, j = task % 24;
        float a = 0.f;
        for (int r = 0; r < cnt; r++) a += tile[r * 24 + i] * tile[r * 24 + j];
        return a;
    }
    int k = task - 576;
    float a = 0.f;
    for (int r = 0; r < cnt; r++) a += tile[r * 24 + k];
    return a;
}
__global__ void k_moments(const float* __restrict__ feats, float* __restrict__ ws) {
    __shared__ float tile[MROWS * C_IN];
    int t = threadIdx.x;
    float acc0 = 0.f, acc1 = 0.f, acc2 = 0.f;
    int nChunks = (N_PTS + MROWS - 1) / MROWS;
    for (int ch = blockIdx.x; ch < nChunks; ch += gridDim.x) {
        int r0 = ch * MROWS;
        int cnt = min(MROWS, N_PTS - r0);
        __syncthreads();
        for (int e = t; e < cnt * C_IN; e += 256) tile[e] = feats[(size_t)r0 * C_IN + e];
        __syncthreads();
        acc0 += task_acc(tile, cnt, t);
        acc1 += task_acc(tile, cnt, t + 256);
        if (t < 88) acc2 += task_acc(tile, cnt, t + 512);
    }
    // flush: tasks 0..575 -> M1, 576..599 -> mu1
    {
        int task = t;
        atomicAdd(&ws[M1_O + task], acc0);
    }
    {
        int task = t + 256;  // always < 576
        atomicAdd(&ws[M1_O + task], acc1);
    }
    if (t < 88) {
        int task = t + 512;
        if (task < 576) atomicAdd(&ws[M1_O + task], acc2);
        else            atomicAdd(&ws[MU1_O + task - 576], acc2);
    }
}

// ---- K2: BN1 closed form: mean1 = mu.W1/N, E[y^2] = w^T (M/N) w
__global__ void k_fin1(const float* __restrict__ w1, const float* __restrict__ g1,
                       const float* __restrict__ b1, float* __restrict__ ws) {
    int c = threadIdx.x;
    if (c >= C_HID) return;
    float wc[C_IN];
    for (int k = 0; k < C_IN; k++) wc[k] = w1[k * C_HID + c];
    const float invN = 1.f / (float)N_PTS;
    float mean = 0.f;
    for (int k = 0; k < C_IN; k++) mean += ws[MU1_O + k] * wc[k];
    mean *= invN;
    float e2 = 0.f;
    for (int i = 0; i < C_IN; i++) {
        float s = 0.f;
        for (int j = 0; j < C_IN; j++) s += ws[M1_O + i * 24 + j] * wc[j];
        e2 += wc[i] * s;
    }
    e2 *= invN;
    float var = e2 - mean * mean;
    float s1 = g1[c] * rsqrtf(var + EPSV);
    ws[SC1_O + c] = s1;
    ws[SH1_O + c] = b1[c] - mean * s1;
}

// ---- K3: GEMM1 (N,24)@(24,144) fused BN1 + relu6 -> x1n
__global__ void k_gemm1(const float* __restrict__ feats, const float* __restrict__ w1,
                        float* __restrict__ ws) {
    __shared__ float4 w1s[C_IN * G4_HID];
    __shared__ float4 sc[G4_HID], sh[G4_HID];
    int t = threadIdx.x;
    const float4* w1v = (const float4*)w1;
    for (int e = t; e < C_IN * G4_HID; e += 256) w1s[e] = w1v[e];
    if (t < G4_HID) {
        sc[t] = ((const float4*)(ws + SC1_O))[t];
        sh[t] = ((const float4*)(ws + SH1_O))[t];
    }
    __syncthreads();
    float4* x1v = (float4*)(ws + X1N_OFF);
    const int T = N_PTS * G4_HID;
    for (int tau = blockIdx.x * 256 + t; tau < T; tau += gridDim.x * 256) {
        int p = tau / G4_HID;
        int g = tau % G4_HID;
        const float4* fr = (const float4*)(feats + (size_t)p * C_IN);
        float4 acc = f4z();
#pragma unroll
        for (int q = 0; q < 6; q++) {
            float4 fq = fr[q];
            acc = f4_fma_s(fq.x, w1s[(4 * q + 0) * G4_HID + g], acc);
            acc = f4_fma_s(fq.y, w1s[(4 * q + 1) * G4_HID + g], acc);
            acc = f4_fma_s(fq.z, w1s[(4 * q + 2) * G4_HID + g], acc);
            acc = f4_fma_s(fq.w, w1s[(4 * q + 3) * G4_HID + g], acc);
        }
        x1v[tau] = f4_clamp6(f4_fma4(acc, sc[g], sh[g]));
    }
}

// ---- K4: channelwise 3x3 conv as gather + fused BN2 stat accumulation
__global__ void k_conv(const float* __restrict__ w2, const int* __restrict__ in_idx,
                       float* __restrict__ ws) {
    __shared__ float4 w2s[KSZ * G4_HID];
    __shared__ float lsum[C_HID], lsq[C_HID];
    int t = threadIdx.x;
    for (int e = t; e < KSZ * G4_HID; e += 256) w2s[e] = ((const float4*)w2)[e];
    if (t < C_HID) { lsum[t] = 0.f; lsq[t] = 0.f; }
    __syncthreads();
    const float4* x1v = (const float4*)(ws + X1N_OFF);
    float4* x2v = (float4*)(ws + X2_OFF);
    bool active = t < 252;
    int pt = t / 36, g = t % 36;   // g fixed per thread across iterations
    float4 rs = f4z(), rq = f4z();
    int nChunks = (N_PTS + 6) / 7;
    for (int ch = blockIdx.x; ch < nChunks; ch += gridDim.x) {
        int p = ch * 7 + pt;
        if (active && p < N_PTS) {
            int idxs[KSZ];
#pragma unroll
            for (int k = 0; k < KSZ; k++) idxs[k] = in_idx[k * N_PTS + p];
            float4 acc = f4z();
#pragma unroll
            for (int k = 0; k < KSZ; k++) {
                float4 v = x1v[(size_t)idxs[k] * G4_HID + g];  // idx==N -> zero sentinel
                acc = f4_fma4(w2s[k * G4_HID + g], v, acc);
            }
            x2v[(size_t)p * G4_HID + g] = acc;
            rs = f4_add(rs, acc);
            rq = f4_fma4(acc, acc, rq);
        }
    }
    if (active) {
        atomicAdd(&lsum[4 * g + 0], rs.x); atomicAdd(&lsum[4 * g + 1], rs.y);
        atomicAdd(&lsum[4 * g + 2], rs.z); atomicAdd(&lsum[4 * g + 3], rs.w);
        atomicAdd(&lsq[4 * g + 0], rq.x);  atomicAdd(&lsq[4 * g + 1], rq.y);
        atomicAdd(&lsq[4 * g + 2], rq.z);  atomicAdd(&lsq[4 * g + 3], rq.w);
    }
    __syncthreads();
    if (t < C_HID) {
        atomicAdd(&ws[SUM2_O + t], lsum[t]);
        atomicAdd(&ws[SQ2_O + t], lsq[t]);
    }
}

// ---- K5: BN2 finalize
__global__ void k_fin2(const float* __restrict__ g2, const float* __restrict__ b2,
                       float* __restrict__ ws) {
    int c = threadIdx.x;
    if (c >= C_HID) return;
    const float invN = 1.f / (float)N_PTS;
    float mean = ws[SUM2_O + c] * invN;
    float var = ws[SQ2_O + c] * invN - mean * mean;
    float s = g2[c] * rsqrtf(var + EPSV);
    ws[SC2_O + c] = s;
    ws[SH2_O + c] = b2[c] - mean * s;
}

// ---- K6: GEMM2 (N,144)@(144,24) with BN2+relu6 applied on the fly -> y3 (raw)
__global__ void k_gemm2(const float* __restrict__ w3, float* __restrict__ ws) {
    __shared__ float4 w3s[C_HID * G4_OUT];
    __shared__ float4 sc2[G4_HID], sh2[G4_HID];
    int t = threadIdx.x;
    for (int e = t; e < C_HID * G4_OUT; e += 256) w3s[e] = ((const float4*)w3)[e];
    if (t < G4_HID) {
        sc2[t] = ((const float4*)(ws + SC2_O))[t];
        sh2[t] = ((const float4*)(ws + SH2_O))[t];
    }
    __syncthreads();
    const float4* x2v = (const float4*)(ws + X2_OFF);
    float4* y3v = (float4*)(ws + Y3_OFF);
    int gtid = blockIdx.x * 256 + t;
    int r0 = gtid * 2, r1 = r0 + 1;
    bool v0 = r0 < N_PTS, v1 = r1 < N_PTS;
    float4 a0[G4_OUT], a1[G4_OUT];
#pragma unroll
    for (int c4 = 0; c4 < G4_OUT; c4++) { a0[c4] = f4z(); a1[c4] = f4z(); }
    for (int h4 = 0; h4 < G4_HID; h4++) {
        float4 xa = v0 ? x2v[(size_t)r0 * G4_HID + h4] : f4z();
        float4 xb = v1 ? x2v[(size_t)r1 * G4_HID + h4] : f4z();
        float4 s = sc2[h4], b = sh2[h4];
        xa = f4_clamp6(f4_fma4(xa, s, b));
        xb = f4_clamp6(f4_fma4(xb, s, b));
#pragma unroll
        for (int e = 0; e < 4; e++) {
            int h = h4 * 4 + e;
            float fa = f4_get(xa, e), fb = f4_get(xb, e);
#pragma unroll
            for (int c4 = 0; c4 < G4_OUT; c4++) {
                float4 w = w3s[h * G4_OUT + c4];
                a0[c4] = f4_fma_s(fa, w, a0[c4]);
                a1[c4] = f4_fma_s(fb, w, a1[c4]);
            }
        }
    }
    if (v0) {
#pragma unroll
        for (int c4 = 0; c4 < G4_OUT; c4++) y3v[(size_t)r0 * G4_OUT + c4] = a0[c4];
    }
    if (v1) {
#pragma unroll
        for (int c4 = 0; c4 < G4_OUT; c4++) y3v[(size_t)r1 * G4_OUT + c4] = a1[c4];
    }
}

// ---- K7: BN3 stats over y3 (channel-stable mapping: blockDim=192, c = t%24)
__global__ void k_red3(float* __restrict__ ws) {
    int t = threadIdx.x;  // blockDim 192
    const float* y3 = ws + Y3_OFF;
    float rs = 0.f, rq = 0.f;
    const int total = N_PTS * C_OUT;
    for (int e = blockIdx.x * 192 + t; e < total; e += gridDim.x * 192) {
        float v = y3[e];
        rs += v; rq += v * v;
    }
    __shared__ float ls[192], lq[192];
    ls[t] = rs; lq[t] = rq;
    __syncthreads();
    if (t < C_OUT) {
        float s = 0.f, q = 0.f;
        for (int u = t; u < 192; u += C_OUT) { s += ls[u]; q += lq[u]; }
        atomicAdd(&ws[SUM3_O + t], s);
        atomicAdd(&ws[SQ3_O + t], q);
    }
}

// ---- K8: BN3 finalize
__global__ void k_fin3(const float* __restrict__ g3, const float* __restrict__ b3,
                       float* __restrict__ ws) {
    int c = threadIdx.x;
    if (c >= C_OUT) return;
    const float invN = 1.f / (float)N_PTS;
    float mean = ws[SUM3_O + c] * invN;
    float var = ws[SQ3_O + c] * invN - mean * mean;
    float s = g3[c] * rsqrtf(var + EPSV);
    ws[SC3_O + c] = s;
    ws[SH3_O + c] = b3[c] - mean * s;
}

// ---- K9: out = bn3(y3) + feats
__global__ void k_out(const float* __restrict__ feats, const float* __restrict__ ws,
                      float* __restrict__ out) {
    int t4 = blockIdx.x * 256 + threadIdx.x;
    const int T = N_PTS * G4_OUT;
    if (t4 >= T) return;
    int g = t4 % G4_OUT;
    float4 y = ((const float4*)(ws + Y3_OFF))[t4];
    float4 s = ((const float4*)(ws + SC3_O))[g];
    float4 b = ((const float4*)(ws + SH3_O))[g];
    float4 f = ((const float4*)feats)[t4];
    ((float4*)out)[t4] = f4_add(f4_fma4(y, s, b), f);
}

extern "C" void kernel_launch(void* const* d_in, const int* in_sizes, int n_in,
                              void* d_out, int out_size, void* d_ws, size_t ws_size,
                              hipStream_t stream) {
    const float* feats = (const float*)d_in[0];
    const float* w1 = (const float*)d_in[1];
    const float* g1 = (const float*)d_in[2];
    const float* b1 = (const float*)d_in[3];
    const float* w2 = (const float*)d_in[4];
    const float* g2 = (const float*)d_in[5];
    const float* b2 = (const float*)d_in[6];
    const float* w3 = (const float*)d_in[7];
    const float* g3 = (const float*)d_in[8];
    const float* b3 = (const float*)d_in[9];
    const int* in_idx = (const int*)d_in[10];
    float* ws = (float*)d_ws;
    float* out = (float*)d_out;

    hipLaunchKernelGGL(k_init, dim3(1), dim3(256), 0, stream, ws);
    hipLaunchKernelGGL(k_moments, dim3(256), dim3(256), 0, stream, feats, ws);
    hipLaunchKernelGGL(k_fin1, dim3(1), dim3(192), 0, stream, w1, g1, b1, ws);
    hipLaunchKernelGGL(k_gemm1, dim3(2048), dim3(256), 0, stream, feats, w1, ws);
    hipLaunchKernelGGL(k_conv, dim3(2048), dim3(256), 0, stream, w2, in_idx, ws);
    hipLaunchKernelGGL(k_fin2, dim3(1), dim3(192), 0, stream, g2, b2, ws);
    hipLaunchKernelGGL(k_gemm2, dim3((N_PTS + 511) / 512), dim3(256), 0, stream, w3, ws);
    hipLaunchKernelGGL(k_red3, dim3(512), dim3(192), 0, stream, ws);
    hipLaunchKernelGGL(k_fin3, dim3(1), dim3(64), 0, stream, g3, b3, ws);
    hipLaunchKernelGGL(k_out, dim3((N_PTS * G4_OUT + 255) / 256), dim3(256), 0, stream,
                       feats, ws, out);
}